// Round 6
// baseline (356.864 us; speedup 1.0000x reference)
//
#include <hip/hip_runtime.h>

// PQN soft-quantization: x[32768,1024] f32, c[1024,256] f32 -> out[32768,1024] f32
// D=1024, M=8 subspaces of L=128, K=256 codes, logits scaled by 2*ALPHA=20.
//
// 16x16x32 f16 MFMA pipeline sized to fit 128 arch VGPRs (no spill; rounds 2/4/5
// showed hipcc caps VGPR at 128 for 512-thread blocks and spills ~90 regs).
// One block per CU (128 KB LDS), 8 waves, 2/SIMD. Each wave-iter = 16 samples:
//   phase 1: z^T[256 codes][16 samples] = cs^T . x^T  (A = LDS csA, B = x in regs)
//   softmax: lane (n,g) owns 64 codes of sample n; in-lane + xor16 + xor32
//   phase 2: out^T[128 l][16 samples]  = cs . w^T     (A = LDS csB, B = packed w)
// csA rows are PERMUTED (rho = 32a+16j+4g+r holds code 32a+8g+4j+r) so that the
// phase-2 B-fragment is exactly the packed phase-1 accumulator words in order:
// pb(ks2) = {P[4ks2..4ks2+3]}. Softmax is order-invariant, so no shuffles at all.

#define D_  1024
#define K_  256
#define L_  128

typedef _Float16 f16;
typedef f16 f16x8 __attribute__((ext_vector_type(8)));
typedef f16 f16x4 __attribute__((ext_vector_type(4)));
typedef f16 f16x2 __attribute__((ext_vector_type(2)));
typedef float f32x4 __attribute__((ext_vector_type(4)));
typedef unsigned int u32;

__global__ __launch_bounds__(512)
void pqn_kernel(const float* __restrict__ x, const float* __restrict__ c,
                float* __restrict__ out) {
    __shared__ unsigned char lds[131072];
    unsigned char* csA = lds;          // [256 rows(perm code)][128 l] f16, 256 B rows, ^=(row&7)<<4
    unsigned char* csB = lds + 65536;  // [128 l][256 codes] f16, 512 B rows, ^=(l&7)<<4

    const int tid  = threadIdx.x;
    const int m    = blockIdx.x >> 5;   // 8 subspaces
    const int bm   = blockIdx.x & 31;   // 32 blocks per subspace
    const int lane = tid & 63;
    const int w    = tid >> 6;          // wave 0..7
    const int n    = lane & 15;         // sample column
    const int g    = lane >> 4;         // quarter-wave (k-group)

    // x loads: lane (n,g) holds row's floats l = 32ks + 8g + {0..7}; per-instr the
    // 4 g-lanes of a row cover a full 64B line pair.
    const float* xbase = x + (size_t)(bm * 1024 + w * 16 + n) * D_ + m * L_ + 8 * g;
    float4 xa[8];
    {
        const float* p = xbase;
        #pragma unroll
        for (int ks = 0; ks < 4; ++ks) {
            xa[2 * ks]     = *reinterpret_cast<const float4*>(p + 32 * ks);
            xa[2 * ks + 1] = *reinterpret_cast<const float4*>(p + 32 * ks + 4);
        }
    }

    // ---- stage codebook subspace m into LDS (f16, both layouts) ----
    const float* cm = c + (size_t)m * L_ * K_;      // cm[l*256 + k]
    {
        const int R0 = tid >> 6;        // 0..7
        const int f  = tid & 63;        // code quad index
        #pragma unroll
        for (int b = 0; b < 8; ++b) {
            int R  = b * 8 + R0;        // 0..63
            int l0 = 2 * R;             // even row
            float4 a  = *reinterpret_cast<const float4*>(cm + (size_t)l0 * K_ + 4 * f);
            float4 bb = *reinterpret_cast<const float4*>(cm + (size_t)(l0 + 1) * K_ + 4 * f);
            f16x4 va = {(f16)a.x, (f16)a.y, (f16)a.z, (f16)a.w};
            f16x4 vb = {(f16)bb.x, (f16)bb.y, (f16)bb.z, (f16)bb.w};
            *reinterpret_cast<f16x4*>(csB + l0 * 512       + ((8 * f) ^ ((l0 & 7) << 4))) = va;
            *reinterpret_cast<f16x4*>(csB + (l0 + 1) * 512 + ((8 * f) ^ (((l0 + 1) & 7) << 4))) = vb;
            #pragma unroll
            for (int j = 0; j < 4; ++j) {
                int cc  = 4 * f + j;
                // rho(c): c = 32a + 8gq + 4jj + r  ->  row = 32a + 16jj + 4gq + r
                int rho = (cc & ~31) + ((cc & 4) << 2) + ((cc & 24) >> 1) + (cc & 3);
                f16x2 t = { va[j], vb[j] };   // elements l0, l0+1 of code cc
                *reinterpret_cast<f16x2*>(csA + rho * 256 + ((2 * l0) ^ ((rho & 7) << 4))) = t;
            }
        }
    }
    __syncthreads();

    #pragma unroll 1
    for (int it = 0; it < 8; ++it) {
        // ---- norm partial (lane's 32 floats) + B1 fragments (k = l = 32ks+8g+i) ----
        float ss = 0.f;
        f16x8 bf[4];
        #pragma unroll
        for (int ks = 0; ks < 4; ++ks) {
            float4 lo = xa[2 * ks], hi = xa[2 * ks + 1];
            ss = fmaf(lo.x, lo.x, ss); ss = fmaf(lo.y, lo.y, ss);
            ss = fmaf(lo.z, lo.z, ss); ss = fmaf(lo.w, lo.w, ss);
            ss = fmaf(hi.x, hi.x, ss); ss = fmaf(hi.y, hi.y, ss);
            ss = fmaf(hi.z, hi.z, ss); ss = fmaf(hi.w, hi.w, ss);
            bf[ks][0] = (f16)lo.x; bf[ks][1] = (f16)lo.y;
            bf[ks][2] = (f16)lo.z; bf[ks][3] = (f16)lo.w;
            bf[ks][4] = (f16)hi.x; bf[ks][5] = (f16)hi.y;
            bf[ks][6] = (f16)hi.z; bf[ks][7] = (f16)hi.w;
        }
        ss += __shfl_xor(ss, 16);
        ss += __shfl_xor(ss, 32);
        const float fac = 20.0f / fmaxf(sqrtf(ss), 1e-12f);

        // ---- phase 1: acc[ct][r] = z[csA row 16ct+4g+r][sample n] ----
        f32x4 acc[16];
        const f32x4 fzero = {0.f, 0.f, 0.f, 0.f};
        #pragma unroll
        for (int ct = 0; ct < 16; ++ct) acc[ct] = fzero;
        #pragma unroll
        for (int ks = 0; ks < 4; ++ks) {
            #pragma unroll
            for (int ct = 0; ct < 16; ++ct) {
                f16x8 af = *reinterpret_cast<const f16x8*>(
                    csA + (ct * 16 + n) * 256 + ((64 * ks + 16 * g) ^ ((n & 7) << 4)));
                acc[ct] = __builtin_amdgcn_mfma_f32_16x16x32_f16(af, bf[ks], acc[ct], 0, 0, 0);
            }
        }

        // ---- prefetch next iter's x (latency hidden under softmax + phase 2) ----
        if (it < 7) {
            const float* p = xbase + (size_t)(it + 1) * 128 * D_;
            #pragma unroll
            for (int ks = 0; ks < 4; ++ks) {
                xa[2 * ks]     = *reinterpret_cast<const float4*>(p + 32 * ks);
                xa[2 * ks + 1] = *reinterpret_cast<const float4*>(p + 32 * ks + 4);
            }
        }

        // ---- softmax over 256 codes (lane owns 64 of sample n; order-invariant) ----
        float z0 = -3.0e38f, z1 = -3.0e38f, z2 = -3.0e38f, z3 = -3.0e38f;
        #pragma unroll
        for (int ct = 0; ct < 16; ++ct) {
            z0 = fmaxf(z0, acc[ct][0]); z1 = fmaxf(z1, acc[ct][1]);
            z2 = fmaxf(z2, acc[ct][2]); z3 = fmaxf(z3, acc[ct][3]);
        }
        float zm = fmaxf(fmaxf(z0, z1), fmaxf(z2, z3));
        zm = fmaxf(zm, __shfl_xor(zm, 16));
        zm = fmaxf(zm, __shfl_xor(zm, 32));
        const float nfz = -fac * zm;

        float s0 = 0.f, s1 = 0.f, s2 = 0.f, s3 = 0.f;
        #pragma unroll
        for (int ct = 0; ct < 16; ++ct) {
            float p0 = __expf(fmaf(acc[ct][0], fac, nfz));
            float p1 = __expf(fmaf(acc[ct][1], fac, nfz));
            float p2 = __expf(fmaf(acc[ct][2], fac, nfz));
            float p3 = __expf(fmaf(acc[ct][3], fac, nfz));
            acc[ct][0] = p0; acc[ct][1] = p1; acc[ct][2] = p2; acc[ct][3] = p3;
            s0 += p0; s1 += p1; s2 += p2; s3 += p3;
        }
        float S = (s0 + s1) + (s2 + s3);
        S += __shfl_xor(S, 16);
        S += __shfl_xor(S, 32);
        const float invS = 1.0f / S;

        // ---- pack: P[2t]=(p0,p1), P[2t+1]=(p2,p3); phase-2 frag = P[4ks2..4ks2+3] ----
        u32 P[32];
        #pragma unroll
        for (int ct = 0; ct < 16; ++ct) {
            P[2 * ct]     = __builtin_bit_cast(u32,
                __builtin_amdgcn_cvt_pkrtz(acc[ct][0], acc[ct][1]));
            P[2 * ct + 1] = __builtin_bit_cast(u32,
                __builtin_amdgcn_cvt_pkrtz(acc[ct][2], acc[ct][3]));
        }

        // ---- phase 2: out^T[l][n] = cs . w^T (B-fragments straight from P) ----
        f32x4 acc2[8];
        #pragma unroll
        for (int lt = 0; lt < 8; ++lt) acc2[lt] = fzero;
        #pragma unroll
        for (int ks2 = 0; ks2 < 8; ++ks2) {
            union { f16x8 v; u32 q[4]; } pb;
            pb.q[0] = P[4 * ks2 + 0]; pb.q[1] = P[4 * ks2 + 1];
            pb.q[2] = P[4 * ks2 + 2]; pb.q[3] = P[4 * ks2 + 3];
            #pragma unroll
            for (int lt = 0; lt < 8; ++lt) {
                f16x8 a2 = *reinterpret_cast<const f16x8*>(
                    csB + (lt * 16 + n) * 512 + ((64 * ks2 + 16 * g) ^ ((n & 7) << 4)));
                acc2[lt] = __builtin_amdgcn_mfma_f32_16x16x32_f16(a2, pb.v, acc2[lt], 0, 0, 0);
            }
        }

        // ---- store: l = 16lt + 4g + r; 4 g-lanes cover a 64B line per row ----
        float* po = out + (size_t)(bm * 1024 + it * 128 + w * 16 + n) * D_ + m * L_ + 4 * g;
        #pragma unroll
        for (int lt = 0; lt < 8; ++lt) {
            f32x4 v;
            v[0] = acc2[lt][0] * invS; v[1] = acc2[lt][1] * invS;
            v[2] = acc2[lt][2] * invS; v[3] = acc2[lt][3] * invS;
            __builtin_nontemporal_store(v, reinterpret_cast<f32x4*>(po + 16 * lt));
        }
    }
}

extern "C" void kernel_launch(void* const* d_in, const int* in_sizes, int n_in,
                              void* d_out, int out_size, void* d_ws, size_t ws_size,
                              hipStream_t stream) {
    const float* x = (const float*)d_in[0];   // [32768, 1024] f32
    const float* c = (const float*)d_in[1];   // [1024, 256]   f32
    float* out = (float*)d_out;               // [32768, 1024] f32
    (void)in_sizes; (void)n_in; (void)out_size; (void)d_ws; (void)ws_size;

    pqn_kernel<<<dim3(256), dim3(512), 0, stream>>>(x, c, out);
}

// Round 7
// 332.694 us; speedup vs baseline: 1.0726x; 1.0726x over previous
//
#include <hip/hip_runtime.h>

// PQN soft-quantization: x[32768,1024] f32, c[1024,256] f32 -> out[32768,1024] f32
// D=1024, M=8 subspaces of L=128, K=256 codes, logits scaled by 2*ALPHA=20.
//
// 16x16x32 f16 MFMA pipeline. 256-thread blocks + __launch_bounds__(256,1):
// the ONLY config observed to get a 256-VGPR budget (rounds 2/4/5/6: every
// 512-thread variant was capped at 128 VGPRs and spilled ~45KB/wave-iter to
// scratch, showing as +300..740 MB of HBM FETCH). 4 waves/block, 1 block/CU
// (128 KB LDS), grid 512 = 2 passes.
// Each wave-iter = 16 samples:
//   phase 1: z^T[256 codes][16 samples] = cs^T . x^T  (A = LDS csA, B = x in regs)
//   softmax: lane (n,g) owns 64 codes of sample n; in-lane + xor16 + xor32
//   phase 2: out^T[128 l][16 samples]  = cs . w^T     (A = LDS csB, B = packed w)
// csA rows are PERMUTED (rho = 32a+16j+4g+r holds code 32a+8g+4j+r) so the
// phase-2 B-fragment is exactly the packed phase-1 accumulator words in order:
// pb(ks2) = {P[4ks2..4ks2+3]}. Softmax is order-invariant -> no shuffles at all.

#define D_  1024
#define K_  256
#define L_  128

typedef _Float16 f16;
typedef f16 f16x8 __attribute__((ext_vector_type(8)));
typedef f16 f16x4 __attribute__((ext_vector_type(4)));
typedef f16 f16x2 __attribute__((ext_vector_type(2)));
typedef float f32x4 __attribute__((ext_vector_type(4)));
typedef unsigned int u32;

__global__ __launch_bounds__(256, 1)
void pqn_kernel(const float* __restrict__ x, const float* __restrict__ c,
                float* __restrict__ out) {
    __shared__ unsigned char lds[131072];
    unsigned char* csA = lds;          // [256 rows(perm code)][128 l] f16, 256 B rows, ^=(row&7)<<4
    unsigned char* csB = lds + 65536;  // [128 l][256 codes] f16, 512 B rows, ^=(l&7)<<4

    const int tid  = threadIdx.x;
    const int m    = blockIdx.x >> 6;   // 8 subspaces, 64 blocks each
    const int bm   = blockIdx.x & 63;
    const int lane = tid & 63;
    const int w    = tid >> 6;          // wave 0..3
    const int n    = lane & 15;         // sample column
    const int g    = lane >> 4;         // quarter-wave (k-group)

    // x loads: lane (n,g) holds row's floats l = 32ks + 8g + {0..7}; the 4
    // g-lanes of a row cover a contiguous 128B chunk per ks (line-perfect).
    const float* xbase = x + (size_t)(bm * 512 + w * 16 + n) * D_ + m * L_ + 8 * g;
    float4 xa[8];
    {
        const float* p = xbase;
        #pragma unroll
        for (int ks = 0; ks < 4; ++ks) {
            xa[2 * ks]     = *reinterpret_cast<const float4*>(p + 32 * ks);
            xa[2 * ks + 1] = *reinterpret_cast<const float4*>(p + 32 * ks + 4);
        }
    }

    // ---- stage codebook subspace m into LDS (f16, both layouts) ----
    const float* cm = c + (size_t)m * L_ * K_;      // cm[l*256 + k]
    {
        const int R0 = tid >> 6;        // 0..3
        const int f  = tid & 63;        // code quad index
        #pragma unroll
        for (int b = 0; b < 16; ++b) {
            int R  = b * 4 + R0;        // 0..63
            int l0 = 2 * R;             // even row
            float4 a  = *reinterpret_cast<const float4*>(cm + (size_t)l0 * K_ + 4 * f);
            float4 bb = *reinterpret_cast<const float4*>(cm + (size_t)(l0 + 1) * K_ + 4 * f);
            f16x4 va = {(f16)a.x, (f16)a.y, (f16)a.z, (f16)a.w};
            f16x4 vb = {(f16)bb.x, (f16)bb.y, (f16)bb.z, (f16)bb.w};
            *reinterpret_cast<f16x4*>(csB + l0 * 512       + ((8 * f) ^ ((l0 & 7) << 4))) = va;
            *reinterpret_cast<f16x4*>(csB + (l0 + 1) * 512 + ((8 * f) ^ (((l0 + 1) & 7) << 4))) = vb;
            #pragma unroll
            for (int j = 0; j < 4; ++j) {
                int cc  = 4 * f + j;
                // rho(c): c = 32a + 8gq + 4jj + r  ->  row = 32a + 16jj + 4gq + r
                int rho = (cc & ~31) + ((cc & 4) << 2) + ((cc & 24) >> 1) + (cc & 3);
                f16x2 t = { va[j], vb[j] };   // elements l0, l0+1 of code cc
                *reinterpret_cast<f16x2*>(csA + rho * 256 + ((2 * l0) ^ ((rho & 7) << 4))) = t;
            }
        }
    }
    __syncthreads();

    #pragma unroll 1
    for (int it = 0; it < 8; ++it) {
        // ---- norm partial (lane's 32 floats) + B1 fragments (k = l = 32ks+8g+i) ----
        float ss = 0.f;
        f16x8 bf[4];
        #pragma unroll
        for (int ks = 0; ks < 4; ++ks) {
            float4 lo = xa[2 * ks], hi = xa[2 * ks + 1];
            ss = fmaf(lo.x, lo.x, ss); ss = fmaf(lo.y, lo.y, ss);
            ss = fmaf(lo.z, lo.z, ss); ss = fmaf(lo.w, lo.w, ss);
            ss = fmaf(hi.x, hi.x, ss); ss = fmaf(hi.y, hi.y, ss);
            ss = fmaf(hi.z, hi.z, ss); ss = fmaf(hi.w, hi.w, ss);
            bf[ks][0] = (f16)lo.x; bf[ks][1] = (f16)lo.y;
            bf[ks][2] = (f16)lo.z; bf[ks][3] = (f16)lo.w;
            bf[ks][4] = (f16)hi.x; bf[ks][5] = (f16)hi.y;
            bf[ks][6] = (f16)hi.z; bf[ks][7] = (f16)hi.w;
        }
        ss += __shfl_xor(ss, 16);
        ss += __shfl_xor(ss, 32);
        const float fac = 20.0f / fmaxf(sqrtf(ss), 1e-12f);

        // ---- phase 1: acc[ct][r] = z[csA row 16ct+4g+r][sample n] ----
        f32x4 acc[16];
        const f32x4 fzero = {0.f, 0.f, 0.f, 0.f};
        #pragma unroll
        for (int ct = 0; ct < 16; ++ct) acc[ct] = fzero;
        #pragma unroll
        for (int ks = 0; ks < 4; ++ks) {
            #pragma unroll
            for (int ct = 0; ct < 16; ++ct) {
                f16x8 af = *reinterpret_cast<const f16x8*>(
                    csA + (ct * 16 + n) * 256 + ((64 * ks + 16 * g) ^ ((n & 7) << 4)));
                acc[ct] = __builtin_amdgcn_mfma_f32_16x16x32_f16(af, bf[ks], acc[ct], 0, 0, 0);
            }
        }

        // ---- prefetch next iter's x (latency hidden under softmax + phase 2) ----
        if (it < 7) {
            const float* p = xbase + (size_t)(it + 1) * 64 * D_;
            #pragma unroll
            for (int ks = 0; ks < 4; ++ks) {
                xa[2 * ks]     = *reinterpret_cast<const float4*>(p + 32 * ks);
                xa[2 * ks + 1] = *reinterpret_cast<const float4*>(p + 32 * ks + 4);
            }
        }

        // ---- softmax over 256 codes (lane owns 64 of sample n; order-invariant) ----
        float z0 = -3.0e38f, z1 = -3.0e38f, z2 = -3.0e38f, z3 = -3.0e38f;
        #pragma unroll
        for (int ct = 0; ct < 16; ++ct) {
            z0 = fmaxf(z0, acc[ct][0]); z1 = fmaxf(z1, acc[ct][1]);
            z2 = fmaxf(z2, acc[ct][2]); z3 = fmaxf(z3, acc[ct][3]);
        }
        float zm = fmaxf(fmaxf(z0, z1), fmaxf(z2, z3));
        zm = fmaxf(zm, __shfl_xor(zm, 16));
        zm = fmaxf(zm, __shfl_xor(zm, 32));
        const float nfz = -fac * zm;

        float s0 = 0.f, s1 = 0.f, s2 = 0.f, s3 = 0.f;
        #pragma unroll
        for (int ct = 0; ct < 16; ++ct) {
            float p0 = __expf(fmaf(acc[ct][0], fac, nfz));
            float p1 = __expf(fmaf(acc[ct][1], fac, nfz));
            float p2 = __expf(fmaf(acc[ct][2], fac, nfz));
            float p3 = __expf(fmaf(acc[ct][3], fac, nfz));
            acc[ct][0] = p0; acc[ct][1] = p1; acc[ct][2] = p2; acc[ct][3] = p3;
            s0 += p0; s1 += p1; s2 += p2; s3 += p3;
        }
        float S = (s0 + s1) + (s2 + s3);
        S += __shfl_xor(S, 16);
        S += __shfl_xor(S, 32);
        const float invS = 1.0f / S;

        // ---- pack: P[2t]=(p0,p1), P[2t+1]=(p2,p3); phase-2 frag = P[4ks2..4ks2+3] ----
        u32 P[32];
        #pragma unroll
        for (int ct = 0; ct < 16; ++ct) {
            P[2 * ct]     = __builtin_bit_cast(u32,
                __builtin_amdgcn_cvt_pkrtz(acc[ct][0], acc[ct][1]));
            P[2 * ct + 1] = __builtin_bit_cast(u32,
                __builtin_amdgcn_cvt_pkrtz(acc[ct][2], acc[ct][3]));
        }

        // ---- phase 2: out^T[l][n] = cs . w^T (B-fragments straight from P) ----
        f32x4 acc2[8];
        #pragma unroll
        for (int lt = 0; lt < 8; ++lt) acc2[lt] = fzero;
        #pragma unroll
        for (int ks2 = 0; ks2 < 8; ++ks2) {
            union { f16x8 v; u32 q[4]; } pb;
            pb.q[0] = P[4 * ks2 + 0]; pb.q[1] = P[4 * ks2 + 1];
            pb.q[2] = P[4 * ks2 + 2]; pb.q[3] = P[4 * ks2 + 3];
            #pragma unroll
            for (int lt = 0; lt < 8; ++lt) {
                f16x8 a2 = *reinterpret_cast<const f16x8*>(
                    csB + (lt * 16 + n) * 512 + ((64 * ks2 + 16 * g) ^ ((n & 7) << 4)));
                acc2[lt] = __builtin_amdgcn_mfma_f32_16x16x32_f16(a2, pb.v, acc2[lt], 0, 0, 0);
            }
        }

        // ---- store: l = 16lt + 4g + r; 4 g-lanes cover a 64B line per row ----
        float* po = out + (size_t)(bm * 512 + it * 64 + w * 16 + n) * D_ + m * L_ + 4 * g;
        #pragma unroll
        for (int lt = 0; lt < 8; ++lt) {
            f32x4 v;
            v[0] = acc2[lt][0] * invS; v[1] = acc2[lt][1] * invS;
            v[2] = acc2[lt][2] * invS; v[3] = acc2[lt][3] * invS;
            __builtin_nontemporal_store(v, reinterpret_cast<f32x4*>(po + 16 * lt));
        }
    }
}

extern "C" void kernel_launch(void* const* d_in, const int* in_sizes, int n_in,
                              void* d_out, int out_size, void* d_ws, size_t ws_size,
                              hipStream_t stream) {
    const float* x = (const float*)d_in[0];   // [32768, 1024] f32
    const float* c = (const float*)d_in[1];   // [1024, 256]   f32
    float* out = (float*)d_out;               // [32768, 1024] f32
    (void)in_sizes; (void)n_in; (void)out_size; (void)d_ws; (void)ws_size;

    pqn_kernel<<<dim3(512), dim3(256), 0, stream>>>(x, c, out);
}

// Round 8
// 324.575 us; speedup vs baseline: 1.0995x; 1.0250x over previous
//
#include <hip/hip_runtime.h>

// PQN soft-quantization: x[32768,1024] f32, c[1024,256] f32 -> out[32768,1024] f32
// D=1024, M=8 subspaces of L=128, K=256 codes, logits scaled by 2*ALPHA=20.
//
// 16x16x32 f16 MFMA pipeline. 256-thread blocks + __launch_bounds__(256,1)
// (verified 256-VGPR budget, no spill). 4 waves/block, 1 block/CU (128 KB LDS),
// grid 256 = single generation, 16 iters/block (1024 rows each).
// R8 experiment vs R7: plain stores (no nontemporal; L2 write-back merges the
// 8 adjacent 64-B stores per row -> no partial-atom RMW at HBM) and grid 256
// (halves codebook restage traffic). Everything else identical to R7.
// Each wave-iter = 16 samples:
//   phase 1: z^T[256 codes][16 samples] = cs^T . x^T  (A = LDS csA, B = x in regs)
//   softmax: lane (n,g) owns 64 codes of sample n; in-lane + xor16 + xor32
//   phase 2: out^T[128 l][16 samples]  = cs . w^T     (A = LDS csB, B = packed w)
// csA rows are PERMUTED (rho = 32a+16j+4g+r holds code 32a+8g+4j+r) so the
// phase-2 B-fragment is exactly the packed phase-1 accumulator words in order:
// pb(ks2) = {P[4ks2..4ks2+3]}. Softmax is order-invariant -> no shuffles at all.

#define D_  1024
#define K_  256
#define L_  128

typedef _Float16 f16;
typedef f16 f16x8 __attribute__((ext_vector_type(8)));
typedef f16 f16x4 __attribute__((ext_vector_type(4)));
typedef f16 f16x2 __attribute__((ext_vector_type(2)));
typedef float f32x4 __attribute__((ext_vector_type(4)));
typedef unsigned int u32;

__global__ __launch_bounds__(256, 1)
void pqn_kernel(const float* __restrict__ x, const float* __restrict__ c,
                float* __restrict__ out) {
    __shared__ unsigned char lds[131072];
    unsigned char* csA = lds;          // [256 rows(perm code)][128 l] f16, 256 B rows, ^=(row&7)<<4
    unsigned char* csB = lds + 65536;  // [128 l][256 codes] f16, 512 B rows, ^=(l&7)<<4

    const int tid  = threadIdx.x;
    const int m    = blockIdx.x >> 5;   // 8 subspaces, 32 blocks each
    const int bm   = blockIdx.x & 31;
    const int lane = tid & 63;
    const int w    = tid >> 6;          // wave 0..3
    const int n    = lane & 15;         // sample column
    const int g    = lane >> 4;         // quarter-wave (k-group)

    // x loads: lane (n,g) holds row's floats l = 32ks + 8g + {0..7}; the 4
    // g-lanes of a row cover a contiguous 128B chunk per ks.
    const float* xbase = x + (size_t)(bm * 1024 + w * 16 + n) * D_ + m * L_ + 8 * g;
    float4 xa[8];
    {
        const float* p = xbase;
        #pragma unroll
        for (int ks = 0; ks < 4; ++ks) {
            xa[2 * ks]     = *reinterpret_cast<const float4*>(p + 32 * ks);
            xa[2 * ks + 1] = *reinterpret_cast<const float4*>(p + 32 * ks + 4);
        }
    }

    // ---- stage codebook subspace m into LDS (f16, both layouts) ----
    const float* cm = c + (size_t)m * L_ * K_;      // cm[l*256 + k]
    {
        const int R0 = tid >> 6;        // 0..3
        const int f  = tid & 63;        // code quad index
        #pragma unroll
        for (int b = 0; b < 16; ++b) {
            int R  = b * 4 + R0;        // 0..63
            int l0 = 2 * R;             // even row
            float4 a  = *reinterpret_cast<const float4*>(cm + (size_t)l0 * K_ + 4 * f);
            float4 bb = *reinterpret_cast<const float4*>(cm + (size_t)(l0 + 1) * K_ + 4 * f);
            f16x4 va = {(f16)a.x, (f16)a.y, (f16)a.z, (f16)a.w};
            f16x4 vb = {(f16)bb.x, (f16)bb.y, (f16)bb.z, (f16)bb.w};
            *reinterpret_cast<f16x4*>(csB + l0 * 512       + ((8 * f) ^ ((l0 & 7) << 4))) = va;
            *reinterpret_cast<f16x4*>(csB + (l0 + 1) * 512 + ((8 * f) ^ (((l0 + 1) & 7) << 4))) = vb;
            #pragma unroll
            for (int j = 0; j < 4; ++j) {
                int cc  = 4 * f + j;
                // rho(c): c = 32a + 8gq + 4jj + r  ->  row = 32a + 16jj + 4gq + r
                int rho = (cc & ~31) + ((cc & 4) << 2) + ((cc & 24) >> 1) + (cc & 3);
                f16x2 t = { va[j], vb[j] };   // elements l0, l0+1 of code cc
                *reinterpret_cast<f16x2*>(csA + rho * 256 + ((2 * l0) ^ ((rho & 7) << 4))) = t;
            }
        }
    }
    __syncthreads();

    #pragma unroll 1
    for (int it = 0; it < 16; ++it) {
        // ---- norm partial (lane's 32 floats) + B1 fragments (k = l = 32ks+8g+i) ----
        float ss = 0.f;
        f16x8 bf[4];
        #pragma unroll
        for (int ks = 0; ks < 4; ++ks) {
            float4 lo = xa[2 * ks], hi = xa[2 * ks + 1];
            ss = fmaf(lo.x, lo.x, ss); ss = fmaf(lo.y, lo.y, ss);
            ss = fmaf(lo.z, lo.z, ss); ss = fmaf(lo.w, lo.w, ss);
            ss = fmaf(hi.x, hi.x, ss); ss = fmaf(hi.y, hi.y, ss);
            ss = fmaf(hi.z, hi.z, ss); ss = fmaf(hi.w, hi.w, ss);
            bf[ks][0] = (f16)lo.x; bf[ks][1] = (f16)lo.y;
            bf[ks][2] = (f16)lo.z; bf[ks][3] = (f16)lo.w;
            bf[ks][4] = (f16)hi.x; bf[ks][5] = (f16)hi.y;
            bf[ks][6] = (f16)hi.z; bf[ks][7] = (f16)hi.w;
        }
        ss += __shfl_xor(ss, 16);
        ss += __shfl_xor(ss, 32);
        const float fac = 20.0f / fmaxf(sqrtf(ss), 1e-12f);

        // ---- phase 1: acc[ct][r] = z[csA row 16ct+4g+r][sample n] ----
        f32x4 acc[16];
        const f32x4 fzero = {0.f, 0.f, 0.f, 0.f};
        #pragma unroll
        for (int ct = 0; ct < 16; ++ct) acc[ct] = fzero;
        #pragma unroll
        for (int ks = 0; ks < 4; ++ks) {
            #pragma unroll
            for (int ct = 0; ct < 16; ++ct) {
                f16x8 af = *reinterpret_cast<const f16x8*>(
                    csA + (ct * 16 + n) * 256 + ((64 * ks + 16 * g) ^ ((n & 7) << 4)));
                acc[ct] = __builtin_amdgcn_mfma_f32_16x16x32_f16(af, bf[ks], acc[ct], 0, 0, 0);
            }
        }

        // ---- prefetch next iter's x (latency hidden under softmax + phase 2) ----
        if (it < 15) {
            const float* p = xbase + (size_t)(it + 1) * 64 * D_;
            #pragma unroll
            for (int ks = 0; ks < 4; ++ks) {
                xa[2 * ks]     = *reinterpret_cast<const float4*>(p + 32 * ks);
                xa[2 * ks + 1] = *reinterpret_cast<const float4*>(p + 32 * ks + 4);
            }
        }

        // ---- softmax over 256 codes (lane owns 64 of sample n; order-invariant) ----
        float z0 = -3.0e38f, z1 = -3.0e38f, z2 = -3.0e38f, z3 = -3.0e38f;
        #pragma unroll
        for (int ct = 0; ct < 16; ++ct) {
            z0 = fmaxf(z0, acc[ct][0]); z1 = fmaxf(z1, acc[ct][1]);
            z2 = fmaxf(z2, acc[ct][2]); z3 = fmaxf(z3, acc[ct][3]);
        }
        float zm = fmaxf(fmaxf(z0, z1), fmaxf(z2, z3));
        zm = fmaxf(zm, __shfl_xor(zm, 16));
        zm = fmaxf(zm, __shfl_xor(zm, 32));
        const float nfz = -fac * zm;

        float s0 = 0.f, s1 = 0.f, s2 = 0.f, s3 = 0.f;
        #pragma unroll
        for (int ct = 0; ct < 16; ++ct) {
            float p0 = __expf(fmaf(acc[ct][0], fac, nfz));
            float p1 = __expf(fmaf(acc[ct][1], fac, nfz));
            float p2 = __expf(fmaf(acc[ct][2], fac, nfz));
            float p3 = __expf(fmaf(acc[ct][3], fac, nfz));
            acc[ct][0] = p0; acc[ct][1] = p1; acc[ct][2] = p2; acc[ct][3] = p3;
            s0 += p0; s1 += p1; s2 += p2; s3 += p3;
        }
        float S = (s0 + s1) + (s2 + s3);
        S += __shfl_xor(S, 16);
        S += __shfl_xor(S, 32);
        const float invS = 1.0f / S;

        // ---- pack: P[2t]=(p0,p1), P[2t+1]=(p2,p3); phase-2 frag = P[4ks2..4ks2+3] ----
        u32 P[32];
        #pragma unroll
        for (int ct = 0; ct < 16; ++ct) {
            P[2 * ct]     = __builtin_bit_cast(u32,
                __builtin_amdgcn_cvt_pkrtz(acc[ct][0], acc[ct][1]));
            P[2 * ct + 1] = __builtin_bit_cast(u32,
                __builtin_amdgcn_cvt_pkrtz(acc[ct][2], acc[ct][3]));
        }

        // ---- phase 2: out^T[l][n] = cs . w^T (B-fragments straight from P) ----
        f32x4 acc2[8];
        #pragma unroll
        for (int lt = 0; lt < 8; ++lt) acc2[lt] = fzero;
        #pragma unroll
        for (int ks2 = 0; ks2 < 8; ++ks2) {
            union { f16x8 v; u32 q[4]; } pb;
            pb.q[0] = P[4 * ks2 + 0]; pb.q[1] = P[4 * ks2 + 1];
            pb.q[2] = P[4 * ks2 + 2]; pb.q[3] = P[4 * ks2 + 3];
            #pragma unroll
            for (int lt = 0; lt < 8; ++lt) {
                f16x8 a2 = *reinterpret_cast<const f16x8*>(
                    csB + (lt * 16 + n) * 512 + ((64 * ks2 + 16 * g) ^ ((n & 7) << 4)));
                acc2[lt] = __builtin_amdgcn_mfma_f32_16x16x32_f16(a2, pb.v, acc2[lt], 0, 0, 0);
            }
        }

        // ---- store (PLAIN, write-back L2 merges the 8 adjacent 64-B lines) ----
        float* po = out + (size_t)(bm * 1024 + it * 64 + w * 16 + n) * D_ + m * L_ + 4 * g;
        #pragma unroll
        for (int lt = 0; lt < 8; ++lt) {
            f32x4 v;
            v[0] = acc2[lt][0] * invS; v[1] = acc2[lt][1] * invS;
            v[2] = acc2[lt][2] * invS; v[3] = acc2[lt][3] * invS;
            *reinterpret_cast<f32x4*>(po + 16 * lt) = v;
        }
    }
}

extern "C" void kernel_launch(void* const* d_in, const int* in_sizes, int n_in,
                              void* d_out, int out_size, void* d_ws, size_t ws_size,
                              hipStream_t stream) {
    const float* x = (const float*)d_in[0];   // [32768, 1024] f32
    const float* c = (const float*)d_in[1];   // [1024, 256]   f32
    float* out = (float*)d_out;               // [32768, 1024] f32
    (void)in_sizes; (void)n_in; (void)out_size; (void)d_ws; (void)ws_size;

    pqn_kernel<<<dim3(256), dim3(256), 0, stream>>>(x, c, out);
}